// Round 1
// baseline (149.090 us; speedup 1.0000x reference)
//
#include <hip/hip_runtime.h>

#define B_ 256
#define N_ 64
#define T_ 60
#define D_ 128
#define H_ 128

typedef __attribute__((ext_vector_type(8))) short short8;
typedef __attribute__((ext_vector_type(4))) float f32x4;

__device__ __forceinline__ unsigned short f2bf(float f) {
  unsigned int u = __builtin_bit_cast(unsigned int, f);
  u = u + 0x7FFFu + ((u >> 16) & 1u);   // round-to-nearest-even
  return (unsigned short)(u >> 16);
}

__device__ __forceinline__ float tanh_fast(float x) {
  // tanh(x) = 1 - 2/(exp(2x)+1);  exp(2x) = 2^(x*2/ln2)
  float e = __builtin_amdgcn_exp2f(x * 2.885390081777927f);
  return 1.0f - 2.0f * __builtin_amdgcn_rcpf(e + 1.0f);
}

// Pack W (K=128 x N=128, row-major [k][n]) into bf16 B-fragment order:
// [kt(4)][nt(8)][lane(64)][elem(8)], value = W[kt*32 + 8*(l>>4) + i][nt*16 + (l&15)]
__global__ __launch_bounds__(256) void prep_weights(
    const float* __restrict__ sg_w1, const float* __restrict__ tg_w1,
    unsigned short* __restrict__ wfrag) {
  int tid = blockIdx.x * 256 + threadIdx.x;   // 0..4095
  if (tid >= 2 * 4 * 8 * 64) return;
  int l  = tid & 63;
  int nt = (tid >> 6) & 7;
  int kt = (tid >> 9) & 3;
  int m  = tid >> 11;
  const float* W = m ? tg_w1 : sg_w1;
  int n  = nt * 16 + (l & 15);
  int k0 = kt * 32 + 8 * (l >> 4);
  unsigned short* dst = wfrag + (size_t)tid * 8;
#pragma unroll
  for (int i = 0; i < 8; ++i) dst[i] = f2bf(W[(k0 + i) * H_ + n]);
}

__global__ __launch_bounds__(256) void spatial_kernel(
    const float* __restrict__ x,
    const short8* __restrict__ wfrag,     // [4][8][64] fragments of sg_w1
    const float* __restrict__ b1,
    const float* __restrict__ w2,
    const float* __restrict__ b2p,
    float* __restrict__ pooled) {
  __shared__ float xs[64][132];
  __shared__ float gate_lds[64];
  __shared__ float alpha_lds[64];
  __shared__ float pp[2][128];

  const int tid = threadIdx.x;
  const int bid = blockIdx.x;
  const int b = bid / T_;
  const int t = bid - b * T_;

  // stage x[b, :, t, :]  (64 rows x 128 f32)
  const float* xbase = x + ((size_t)b * N_ * T_ + t) * D_;
#pragma unroll
  for (int it = 0; it < 8; ++it) {
    int q = it * 256 + tid;          // 0..2047 float4 slots
    int n = q >> 5;
    int c4 = (q & 31) << 2;
    float4 v = *(const float4*)(xbase + (size_t)n * (T_ * D_) + c4);
    *(float4*)(&xs[n][c4]) = v;
  }
  __syncthreads();

  const int l = tid & 63;
  const int w = tid >> 6;
  const int lg = l >> 4;
  const int lr = l & 15;

  float b1v[8], w2v[8];
#pragma unroll
  for (int nt = 0; nt < 8; ++nt) {
    b1v[nt] = b1[nt * 16 + lr];
    w2v[nt] = w2[nt * 16 + lr];
  }
  const float b2 = b2p[0];

  f32x4 acc[8];
#pragma unroll
  for (int nt = 0; nt < 8; ++nt) acc[nt] = (f32x4)(0.0f);

  const int row = 16 * w + lr;       // node index this lane's A-frag covers
#pragma unroll
  for (int kt = 0; kt < 4; ++kt) {
    const int k0 = kt * 32 + 8 * lg;
    float4 a0 = *(const float4*)(&xs[row][k0]);
    float4 a1 = *(const float4*)(&xs[row][k0 + 4]);
    short8 af;
    af[0] = (short)f2bf(a0.x); af[1] = (short)f2bf(a0.y);
    af[2] = (short)f2bf(a0.z); af[3] = (short)f2bf(a0.w);
    af[4] = (short)f2bf(a1.x); af[5] = (short)f2bf(a1.y);
    af[6] = (short)f2bf(a1.z); af[7] = (short)f2bf(a1.w);
#pragma unroll
    for (int nt = 0; nt < 8; ++nt) {
      short8 bf = wfrag[(kt * 8 + nt) * 64 + l];
      acc[nt] = __builtin_amdgcn_mfma_f32_16x16x32_bf16(af, bf, acc[nt], 0, 0, 0);
    }
  }

  // gate[n] = sum_j tanh(h[n][j] + b1[j]) * w2[j] + b2
  // lane holds rows {16w + 4*lg + j}, cols {nt*16 + lr}
#pragma unroll
  for (int j = 0; j < 4; ++j) {
    float s = 0.f;
#pragma unroll
    for (int nt = 0; nt < 8; ++nt) {
      float h = acc[nt][j] + b1v[nt];
      s += tanh_fast(h) * w2v[nt];
    }
    s += __shfl_xor(s, 1);
    s += __shfl_xor(s, 2);
    s += __shfl_xor(s, 4);
    s += __shfl_xor(s, 8);
    if (lr == 0) gate_lds[16 * w + 4 * lg + j] = s + b2;
  }
  __syncthreads();

  // softmax over 64 nodes (each wave computes redundantly; wave0 publishes)
  float g = gate_lds[l];
  float mx = g;
  mx = fmaxf(mx, __shfl_xor(mx, 32));
  mx = fmaxf(mx, __shfl_xor(mx, 16));
  mx = fmaxf(mx, __shfl_xor(mx, 8));
  mx = fmaxf(mx, __shfl_xor(mx, 4));
  mx = fmaxf(mx, __shfl_xor(mx, 2));
  mx = fmaxf(mx, __shfl_xor(mx, 1));
  float p = __builtin_amdgcn_exp2f((g - mx) * 1.4426950408889634f);
  float sm = p;
  sm += __shfl_xor(sm, 32);
  sm += __shfl_xor(sm, 16);
  sm += __shfl_xor(sm, 8);
  sm += __shfl_xor(sm, 4);
  sm += __shfl_xor(sm, 2);
  sm += __shfl_xor(sm, 1);
  float alpha = p / sm;
  if (w == 0) alpha_lds[l] = alpha;
  __syncthreads();

  // pooled[b,t,:] = sum_n alpha[n] * x[n,:]  (fp32, from LDS)
  const int c = tid & 127;
  const int hh = tid >> 7;
  float s = 0.f;
#pragma unroll
  for (int i = 0; i < 32; ++i) {
    int n = 32 * hh + i;
    s += alpha_lds[n] * xs[n][c];
  }
  pp[hh][c] = s;
  __syncthreads();
  if (tid < 128) {
    pooled[((size_t)b * T_ + t) * D_ + tid] = pp[0][tid] + pp[1][tid];
  }
}

__global__ __launch_bounds__(256) void temporal_kernel(
    const float* __restrict__ pooled,
    const short8* __restrict__ wfrag,     // fragments of tg_w1
    const float* __restrict__ b1,
    const float* __restrict__ w2,
    const float* __restrict__ b2p,
    float* __restrict__ out) {
  __shared__ float xs[64][132];
  __shared__ float score_lds[64];
  __shared__ float tw_lds[64];
  __shared__ float pp[2][128];

  const int tid = threadIdx.x;
  const int b = blockIdx.x;

  const float* pb = pooled + (size_t)b * T_ * D_;
#pragma unroll
  for (int it = 0; it < 8; ++it) {
    int q = it * 256 + tid;
    int n = q >> 5;
    int c4 = (q & 31) << 2;
    float4 v = {0.f, 0.f, 0.f, 0.f};
    if (n < T_) v = *(const float4*)(pb + n * D_ + c4);
    *(float4*)(&xs[n][c4]) = v;   // rows 60..63 zero-padded
  }
  __syncthreads();

  const int l = tid & 63;
  const int w = tid >> 6;
  const int lg = l >> 4;
  const int lr = l & 15;

  float b1v[8], w2v[8];
#pragma unroll
  for (int nt = 0; nt < 8; ++nt) {
    b1v[nt] = b1[nt * 16 + lr];
    w2v[nt] = w2[nt * 16 + lr];
  }
  const float b2 = b2p[0];

  f32x4 acc[8];
#pragma unroll
  for (int nt = 0; nt < 8; ++nt) acc[nt] = (f32x4)(0.0f);

  const int row = 16 * w + lr;
#pragma unroll
  for (int kt = 0; kt < 4; ++kt) {
    const int k0 = kt * 32 + 8 * lg;
    float4 a0 = *(const float4*)(&xs[row][k0]);
    float4 a1 = *(const float4*)(&xs[row][k0 + 4]);
    short8 af;
    af[0] = (short)f2bf(a0.x); af[1] = (short)f2bf(a0.y);
    af[2] = (short)f2bf(a0.z); af[3] = (short)f2bf(a0.w);
    af[4] = (short)f2bf(a1.x); af[5] = (short)f2bf(a1.y);
    af[6] = (short)f2bf(a1.z); af[7] = (short)f2bf(a1.w);
#pragma unroll
    for (int nt = 0; nt < 8; ++nt) {
      short8 bf = wfrag[(kt * 8 + nt) * 64 + l];
      acc[nt] = __builtin_amdgcn_mfma_f32_16x16x32_bf16(af, bf, acc[nt], 0, 0, 0);
    }
  }

#pragma unroll
  for (int j = 0; j < 4; ++j) {
    float s = 0.f;
#pragma unroll
    for (int nt = 0; nt < 8; ++nt) {
      float h = acc[nt][j] + b1v[nt];
      s += tanh_fast(h) * w2v[nt];
    }
    s += __shfl_xor(s, 1);
    s += __shfl_xor(s, 2);
    s += __shfl_xor(s, 4);
    s += __shfl_xor(s, 8);
    if (lr == 0) score_lds[16 * w + 4 * lg + j] = s + b2;
  }
  __syncthreads();

  // masked softmax over T=60
  float g = (l < T_) ? score_lds[l] : -3.0e38f;
  float mx = g;
  mx = fmaxf(mx, __shfl_xor(mx, 32));
  mx = fmaxf(mx, __shfl_xor(mx, 16));
  mx = fmaxf(mx, __shfl_xor(mx, 8));
  mx = fmaxf(mx, __shfl_xor(mx, 4));
  mx = fmaxf(mx, __shfl_xor(mx, 2));
  mx = fmaxf(mx, __shfl_xor(mx, 1));
  float p = (l < T_) ? __builtin_amdgcn_exp2f((g - mx) * 1.4426950408889634f) : 0.f;
  float sm = p;
  sm += __shfl_xor(sm, 32);
  sm += __shfl_xor(sm, 16);
  sm += __shfl_xor(sm, 8);
  sm += __shfl_xor(sm, 4);
  sm += __shfl_xor(sm, 2);
  sm += __shfl_xor(sm, 1);
  float tw = p / sm;
  if (w == 0) {
    tw_lds[l] = tw;
    if (l < T_) out[B_ * D_ + b * T_ + l] = tw;   // tw output
  }
  __syncthreads();

  const int c = tid & 127;
  const int hh = tid >> 7;
  float s = 0.f;
#pragma unroll
  for (int i = 0; i < 30; ++i) {
    int tt = 30 * hh + i;
    s += tw_lds[tt] * xs[tt][c];
  }
  pp[hh][c] = s;
  __syncthreads();
  if (tid < 128) out[(size_t)b * D_ + tid] = pp[0][tid] + pp[1][tid];
}

extern "C" void kernel_launch(void* const* d_in, const int* in_sizes, int n_in,
                              void* d_out, int out_size, void* d_ws, size_t ws_size,
                              hipStream_t stream) {
  const float* x     = (const float*)d_in[0];
  const float* sg_w1 = (const float*)d_in[1];
  const float* sg_b1 = (const float*)d_in[2];
  const float* sg_w2 = (const float*)d_in[3];
  const float* sg_b2 = (const float*)d_in[4];
  const float* tg_w1 = (const float*)d_in[5];
  const float* tg_b1 = (const float*)d_in[6];
  const float* tg_w2 = (const float*)d_in[7];
  const float* tg_b2 = (const float*)d_in[8];
  float* out = (float*)d_out;

  unsigned short* wfrag = (unsigned short*)d_ws;            // 2 * 2048 * 8 ushorts = 64 KB
  float* pooled = (float*)((char*)d_ws + 65536);            // B*T*D f32 = 7.86 MB

  prep_weights<<<16, 256, 0, stream>>>(sg_w1, tg_w1, wfrag);
  spatial_kernel<<<B_ * T_, 256, 0, stream>>>(
      x, (const short8*)wfrag, sg_b1, sg_w2, sg_b2, pooled);
  temporal_kernel<<<B_, 256, 0, stream>>>(
      pooled, (const short8*)(wfrag + 16384), tg_b1, tg_w2, tg_b2, out);
}